// Round 4
// baseline (277.327 us; speedup 1.0000x reference)
//
#include <hip/hip_runtime.h>
#include <cstdint>

typedef __bf16 bf16;
typedef __attribute__((ext_vector_type(8))) __bf16 bf16x8;
typedef __attribute__((ext_vector_type(4))) __bf16 bf16x4;
typedef __attribute__((ext_vector_type(4))) float f32x4;

#define NROWS 100000
#define DIM   512
#define NC    400

// ---- workspace layout (bytes) ---- identical to round 3 (proven ws >= 71041536)
#define WS_WP    0u          // packed W bf16: 16*4*448*8 = 229376 elems = 458752 B
#define WS_SUMU  458752u
#define WS_SUMV  459152u
#define WS_DSC   459552u
#define WS_VTZT  459776u     // [112][128] bf16
#define WS_U     524288u     // [100000][128] bf16
#define WS_VT    26124288u   // V^T [100][100000] bf16
#define WS_ZT    46124288u   // Z^T [100][100000] bf16
#define WS_PART  66124288u   // 196 x 12544 bf16
#define WS_NEED  71041536u
#define WS_PART2 WS_WP       // reuse dead wp region after k2

__device__ __forceinline__ void gload_lds16(const void* g, void* l) {
  __builtin_amdgcn_global_load_lds(
      (const __attribute__((address_space(1))) uint32_t*)g,
      (__attribute__((address_space(3))) uint32_t*)l,
      16, 0, 0);
}

// ---- k1: pack W -> [t][g][448 col][8 e] bf16 (28672 B per tile t); zero sums ----
// flat idx = ((t*4+g)*448 + col)*8 + e ; k = t*32 + 4g + (e<4 ? e : 12+e)
__global__ void k1_prep(const float* __restrict__ W, bf16* __restrict__ wp,
                        float* __restrict__ sums) {
  const int idx = blockIdx.x * 256 + threadIdx.x;
  if (idx < 200) sums[idx] = 0.f;
  if (idx >= 16 * 4 * 448 * 8) return;
  const int e = idx & 7;
  int r = idx >> 3;
  const int col = r % 448; r /= 448;
  const int g = r & 3;
  const int t = r >> 2;
  const int k = t * 32 + 4 * g + ((e < 4) ? e : (12 + e));
  wp[idx] = (bf16)((col < NC) ? W[col * DIM + k] : 0.f);
}

// ---- k2: relu(X@Wt+b). BM=64 x BN=448, BK=32, 8 waves.
// All staging via global_load_lds; counted vmcnt keeps next-tile loads in
// flight across the barrier (T3+T4). A staged as f32 with XOR swizzle
// (linear LDS dest, inverse-swizzled global source, swizzled read).
__global__ __launch_bounds__(512, 4) void k2_main(
    const float* __restrict__ X, const bf16* __restrict__ Wp,
    const float* __restrict__ bias, float* __restrict__ out,
    bf16* __restrict__ U, bf16* __restrict__ Vt, bf16* __restrict__ Zt,
    float* __restrict__ sumU, float* __restrict__ sumV) {
  __shared__ __align__(16) float Ab[2][2048];   // [64 rows][32 f32], 8 KB each
  __shared__ __align__(16) bf16  Bb[2][14336];  // [g][448][8], 28 KB each

  const int tid  = threadIdx.x;
  const int lane = tid & 63;
  const int wave = tid >> 6;         // 0..7
  const int wm = wave >> 2;          // 0..1 : 32-row half
  const int wn = wave & 3;           // 0..3 : 112-col quarter
  const int m  = lane & 15;
  const int g  = lane >> 4;
  const int rb = blockIdx.x * 64;

  f32x4 acc[2][7];
#pragma unroll
  for (int i = 0; i < 2; ++i)
#pragma unroll
    for (int j = 0; j < 7; ++j) acc[i][j] = (f32x4){0.f, 0.f, 0.f, 0.f};

  // A staging: chunk = wave (rows 8w..8w+7); lane -> row 8w+(l>>3), bytes (l&7)*16
  // source byte pre-swizzled: ((l&7)*16) ^ ((l>>3)*16)
  const int arow = wave * 8 + (lane >> 3);
  int gr = rb + arow; if (gr > NROWS - 1) gr = NROWS - 1;
  const char* asrc = (const char*)X + (size_t)gr * 2048 + (size_t)(((lane & 7) ^ (lane >> 3)) * 16);
  // B staging: chunks of 1024 B; waves 0-3 take 4, waves 4-7 take 3
  const int bc0 = (wave < 4) ? wave * 4 : 16 + (wave - 4) * 3;
  const int nbc = (wave < 4) ? 4 : 3;
  const char* wpc = (const char*)Wp;

#define STAGE(T, BUF)                                                          \
  do {                                                                         \
    gload_lds16(asrc + (T) * 128, (char*)&Ab[BUF][0] + wave * 1024 + lane * 16); \
    const char* bsrc = wpc + (size_t)(T) * 28672;                              \
    for (int q = 0; q < nbc; ++q)                                              \
      gload_lds16(bsrc + (bc0 + q) * 1024 + lane * 16,                         \
                  (char*)&Bb[BUF][0] + (bc0 + q) * 1024);                      \
  } while (0)

  STAGE(0, 0);

#pragma unroll
  for (int t = 0; t < 16; ++t) {
    const int cur = t & 1;
    if (t < 15) {
      STAGE(t + 1, cur ^ 1);
      // wait for my tile-t loads (oldest), leave tile-t+1 loads in flight;
      // barrier ensures every wave's tile-t loads landed.
      if (wave < 4) asm volatile("s_waitcnt vmcnt(5)\n\ts_barrier" ::: "memory");
      else          asm volatile("s_waitcnt vmcnt(4)\n\ts_barrier" ::: "memory");
    } else {
      asm volatile("s_waitcnt vmcnt(0)\n\ts_barrier" ::: "memory");
    }

    // A fragments (swizzled read, f32 -> bf16)
    const int sw = (m & 7) * 16;
    const char* row0 = (const char*)&Ab[cur][0] + (wm * 32 + m) * 128;
    const char* row1 = row0 + 16 * 128;
    f32x4 a0lo = *(const f32x4*)(row0 + ((16 * g) ^ sw));
    f32x4 a0hi = *(const f32x4*)(row0 + ((64 + 16 * g) ^ sw));
    f32x4 a1lo = *(const f32x4*)(row1 + ((16 * g) ^ sw));
    f32x4 a1hi = *(const f32x4*)(row1 + ((64 + 16 * g) ^ sw));
    bf16x8 af0 = {(bf16)a0lo.x, (bf16)a0lo.y, (bf16)a0lo.z, (bf16)a0lo.w,
                  (bf16)a0hi.x, (bf16)a0hi.y, (bf16)a0hi.z, (bf16)a0hi.w};
    bf16x8 af1 = {(bf16)a1lo.x, (bf16)a1lo.y, (bf16)a1lo.z, (bf16)a1lo.w,
                  (bf16)a1hi.x, (bf16)a1hi.y, (bf16)a1hi.z, (bf16)a1hi.w};

    const bf16* Bc = &Bb[cur][0];
#pragma unroll
    for (int nf = 0; nf < 7; ++nf) {
      const int n = wn * 112 + nf * 16 + m;
      bf16x8 bfr = *(const bf16x8*)(Bc + (g * 448 + n) * 8);
      acc[0][nf] = __builtin_amdgcn_mfma_f32_16x16x32_bf16(af0, bfr, acc[0][nf], 0, 0, 0);
      acc[1][nf] = __builtin_amdgcn_mfma_f32_16x16x32_bf16(af1, bfr, acc[1][nf], 0, 0, 0);
    }
    // protect cur from being restaged (at t+1 it is the gload target again at t+2)
    asm volatile("s_barrier" ::: "memory");
  }
#undef STAGE

  // epilogue: bias+relu, scatter U / Vt / Zt / T, column sums
  float csum[7];
#pragma unroll
  for (int nf = 0; nf < 7; ++nf) csum[nf] = 0.f;

#pragma unroll
  for (int mf = 0; mf < 2; ++mf) {
#pragma unroll
    for (int nf = 0; nf < 7; ++nf) {
      const int c = wn * 112 + nf * 16 + m;
      const float bv = (c < NC) ? bias[c] : 0.f;
#pragma unroll
      for (int r = 0; r < 4; ++r) {
        const int row = rb + wm * 32 + mf * 16 + 4 * g + r;
        float v = fmaxf(acc[mf][nf][r] + bv, 0.f);
        if (row < NROWS) {
          if (c < 128) U[(size_t)row * 128 + c] = (c < 100) ? (bf16)v : (bf16)0.f;
          if (c >= 100 && c < 200) Vt[(size_t)(c - 100) * NROWS + row] = (bf16)v;
          if (c >= 200 && c < 300) Zt[(size_t)(c - 200) * NROWS + row] = (bf16)v;
          if (c >= 300 && c < NC)  out[(size_t)row * 200 + 100 + (c - 300)] = v;
          if (c < 200) csum[nf] += v;
        }
      }
    }
  }
#pragma unroll
  for (int nf = 0; nf < 7; ++nf) {
    float s = csum[nf];
    s += __shfl_xor(s, 16, 64);
    s += __shfl_xor(s, 32, 64);
    if (lane < 16) {
      const int c = wn * 112 + nf * 16 + lane;
      if (c < 100) atomicAdd(&sumU[c], s);
      else if (c < 200) atomicAdd(&sumV[c - 100], s);
    }
  }
}

// ---- k3: partial VtZ per 512-row block via MFMA from Vt/Zt (no LDS) ----
__global__ __launch_bounds__(512) void k3_vtz(
    const bf16* __restrict__ Vt, const bf16* __restrict__ Zt,
    bf16* __restrict__ part) {
  const int lane = threadIdx.x & 63;
  const int wave = threadIdx.x >> 6;
  if (wave >= 7) return;
  const int m = lane & 15, g = lane >> 4;
  const int rbase = blockIdx.x * 512;
  int nks = (NROWS - rbase) >> 5;
  if (nks > 16) nks = 16;

  f32x4 acc[7];
#pragma unroll
  for (int j = 0; j < 7; ++j) acc[j] = (f32x4){0.f, 0.f, 0.f, 0.f};

  const int i2 = wave * 16 + m;
  const bf16* va = Vt + (size_t)i2 * NROWS;
  for (int ks = 0; ks < nks; ++ks) {
    const int k0 = rbase + ks * 32 + 4 * g;
    bf16x4 A0 = *(const bf16x4*)(va + k0);
    bf16x4 A1 = *(const bf16x4*)(va + k0 + 16);
    bf16x8 af = {A0[0], A0[1], A0[2], A0[3], A1[0], A1[1], A1[2], A1[3]};
#pragma unroll
    for (int nf = 0; nf < 7; ++nf) {
      const bf16* zb = Zt + (size_t)(nf * 16 + m) * NROWS + k0;
      bf16x4 B0 = *(const bf16x4*)(zb);
      bf16x4 B1 = *(const bf16x4*)(zb + 16);
      bf16x8 bf_ = {B0[0], B0[1], B0[2], B0[3], B1[0], B1[1], B1[2], B1[3]};
      acc[nf] = __builtin_amdgcn_mfma_f32_16x16x32_bf16(af, bf_, acc[nf], 0, 0, 0);
    }
  }
  bf16* pb = part + (size_t)blockIdx.x * 12544;
#pragma unroll
  for (int nf = 0; nf < 7; ++nf)
#pragma unroll
    for (int r = 0; r < 4; ++r) {
      const int ii = wave * 16 + 4 * g + r;
      const int jj = nf * 16 + m;
      pb[ii * 112 + jj] = (bf16)acc[nf][r];
    }
}

// ---- k4a: Dscale ----
__global__ void k4a_norm(const float* __restrict__ sumU, const float* __restrict__ sumV,
                         float* __restrict__ dsc) {
  const int l = threadIdx.x;  // 64
  float v = 0.f;
  if (l < 50) v = sumU[l] * sumV[l] + sumU[l + 50] * sumV[l + 50];
#pragma unroll
  for (int off = 32; off > 0; off >>= 1) v += __shfl_down(v, off, 64);
  if (l == 0) dsc[0] = 1.f / (v * (1.f / (float)NROWS) + 1e-6f);
}

// ---- k4b1: reduce 196 bf16 partials -> 7 f32 groups (of 28) ----
__global__ void k4b1_reduce(const bf16* __restrict__ part, float* __restrict__ part2) {
  const int b = blockIdx.x;          // 343 = 7*49
  const int grp = b / 49;
  const int off = (b % 49) * 256 + threadIdx.x;
  if (off >= 12544) return;
  float s = 0.f;
#pragma unroll 4
  for (int q = 0; q < 28; ++q)
    s += (float)part[(size_t)(grp * 28 + q) * 12544 + off];
  part2[grp * 12544 + off] = s;
}

// ---- k4b2: final 7-sum, scale by Dscale, store transposed bf16 [j][128] ----
__global__ void k4b2_final(const float* __restrict__ part2, const float* __restrict__ dsc,
                           bf16* __restrict__ vtzt) {
  const int idx = blockIdx.x * 256 + threadIdx.x;   // 49 blocks
  if (idx < 1792) vtzt[(idx >> 4) * 128 + 112 + (idx & 15)] = (bf16)0.f;
  if (idx >= 12544) return;
  const int i = idx / 112;
  const int j = idx % 112;
  float s = 0.f;
#pragma unroll
  for (int grp = 0; grp < 7; ++grp) s += part2[grp * 12544 + idx];
  vtzt[j * 128 + i] = (bf16)(s * dsc[0]);
}

// ---- k5: res = U @ VtZS -> out[:, 0:100] ----
__global__ __launch_bounds__(256) void k5_res(
    const bf16* __restrict__ U, const bf16* __restrict__ vtzt,
    float* __restrict__ out) {
  const int tid = threadIdx.x;
  const int lane = tid & 63;
  const int wave = tid >> 6;
  const int m = lane & 15, g = lane >> 4;
  const int rb = blockIdx.x * 128 + wave * 32;

  f32x4 acc[2][7];
#pragma unroll
  for (int i = 0; i < 2; ++i)
#pragma unroll
    for (int j = 0; j < 7; ++j) acc[i][j] = (f32x4){0.f, 0.f, 0.f, 0.f};

  int r0 = rb + m;      if (r0 > NROWS - 1) r0 = NROWS - 1;
  int r1 = rb + 16 + m; if (r1 > NROWS - 1) r1 = NROWS - 1;
  const bf16* u0 = U + (size_t)r0 * 128 + 4 * g;
  const bf16* u1 = U + (size_t)r1 * 128 + 4 * g;
  const bf16* vb = vtzt + 4 * g;

#pragma unroll
  for (int ks = 0; ks < 4; ++ks) {
    bf16x4 A00 = *(const bf16x4*)(u0 + ks * 32);
    bf16x4 A01 = *(const bf16x4*)(u0 + ks * 32 + 16);
    bf16x4 A10 = *(const bf16x4*)(u1 + ks * 32);
    bf16x4 A11 = *(const bf16x4*)(u1 + ks * 32 + 16);
    bf16x8 af0 = {A00[0], A00[1], A00[2], A00[3], A01[0], A01[1], A01[2], A01[3]};
    bf16x8 af1 = {A10[0], A10[1], A10[2], A10[3], A11[0], A11[1], A11[2], A11[3]};
#pragma unroll
    for (int nf = 0; nf < 7; ++nf) {
      const int n = nf * 16 + m;
      bf16x4 B0 = *(const bf16x4*)(vb + n * 128 + ks * 32);
      bf16x4 B1 = *(const bf16x4*)(vb + n * 128 + ks * 32 + 16);
      bf16x8 bfr = {B0[0], B0[1], B0[2], B0[3], B1[0], B1[1], B1[2], B1[3]};
      acc[0][nf] = __builtin_amdgcn_mfma_f32_16x16x32_bf16(af0, bfr, acc[0][nf], 0, 0, 0);
      acc[1][nf] = __builtin_amdgcn_mfma_f32_16x16x32_bf16(af1, bfr, acc[1][nf], 0, 0, 0);
    }
  }
#pragma unroll
  for (int mf = 0; mf < 2; ++mf)
#pragma unroll
    for (int nf = 0; nf < 7; ++nf)
#pragma unroll
      for (int r = 0; r < 4; ++r) {
        const int row = rb + mf * 16 + 4 * g + r;
        const int c = nf * 16 + m;
        if (row < NROWS && c < 100)
          out[(size_t)row * 200 + c] = acc[mf][nf][r];
      }
}

extern "C" void kernel_launch(void* const* d_in, const int* in_sizes, int n_in,
                              void* d_out, int out_size, void* d_ws, size_t ws_size,
                              hipStream_t stream) {
  const float* X = (const float*)d_in[0];
  const float* W = (const float*)d_in[1];
  const float* b = (const float*)d_in[2];
  float* out = (float*)d_out;
  char* ws = (char*)d_ws;
  if (ws_size < WS_NEED) return;

  bf16* wp     = (bf16*)(ws + WS_WP);
  float* sumU  = (float*)(ws + WS_SUMU);
  float* sumV  = (float*)(ws + WS_SUMV);
  float* dsc   = (float*)(ws + WS_DSC);
  bf16* vtzt   = (bf16*)(ws + WS_VTZT);
  bf16* U      = (bf16*)(ws + WS_U);
  bf16* Vtb    = (bf16*)(ws + WS_VT);
  bf16* Ztb    = (bf16*)(ws + WS_ZT);
  bf16* part   = (bf16*)(ws + WS_PART);
  float* part2 = (float*)(ws + WS_PART2);

  k1_prep<<<896, 256, 0, stream>>>(W, wp, sumU);
  k2_main<<<1563, 512, 0, stream>>>(X, wp, b, out, U, Vtb, Ztb, sumU, sumV);
  k3_vtz<<<196, 512, 0, stream>>>(Vtb, Ztb, part);
  k4a_norm<<<1, 64, 0, stream>>>(sumU, sumV, dsc);
  k4b1_reduce<<<343, 256, 0, stream>>>(part, part2);
  k4b2_final<<<49, 256, 0, stream>>>(part2, dsc, vtzt);
  k5_res<<<782, 256, 0, stream>>>(U, vtzt, out);
}